// Round 1
// 639.409 us; speedup vs baseline: 1.0459x; 1.0459x over previous
//
#include <hip/hip_runtime.h>
#include <hip/hip_bf16.h>

// ---------------- problem constants ----------------
#define TPAD   65656    // t_padded
#define TOUT   65536
#define CCH    384      // channels
#define NROWS  768      // SIZE * C
#define HOP    392
#define NB     168
#define BS     512      // fft block size
#define KPAD   416      // 392 padded to multiple of 32
#define M1     129024   // NROWS * NB
#define M2     131072   // 2 * TOUT

typedef __attribute__((ext_vector_type(8))) _Float16 f16x8;
typedef __attribute__((ext_vector_type(4))) _Float16 f16x4;
typedef __attribute__((ext_vector_type(4))) float    f32x4;
typedef __attribute__((ext_vector_type(8))) float    f32x8;

__device__ __forceinline__ void gload_lds16(const void* g, void* l) {
    __builtin_amdgcn_global_load_lds(
        (__attribute__((address_space(1))) void*)g,
        (__attribute__((address_space(3))) void*)l, 16, 0, 0);
}

// ---------------- h = irfft_backward(kernel_fft, 512) ----------------
__global__ void build_h_kernel(const float* __restrict__ kfft, float* __restrict__ h) {
    __shared__ float Ks[257];
    int j = threadIdx.x;          // 0..511
    if (j < 257) Ks[j] = kfft[j];
    __syncthreads();
    float acc = Ks[0] + ((j & 1) ? -Ks[256] : Ks[256]);
    const float w0 = 6.2831853071795864769f / 512.0f;
    for (int f = 1; f < 256; ++f) {
        int m = (f * j) & 511;            // exact integer phase reduction
        acc += 2.0f * Ks[f] * cosf(w0 * (float)m);
    }
    h[j] = acc * (1.0f / 512.0f);
}

// ---------------- Ht[j][i] = h[(j-i) mod 512], i<392 else 0 ----------------
__global__ void build_ht_kernel(const float* __restrict__ h, _Float16* __restrict__ Ht) {
    int j = blockIdx.x;                               // 0..511
    int i = blockIdx.y * 256 + threadIdx.x;           // 0..511
    if (i >= KPAD) return;
    float v = (i < HOP) ? h[(j - i) & 511] : 0.0f;
    Ht[j * KPAD + i] = (_Float16)v;
}

// ---------------- spT[d][c] = std[c] * vt[c][d] ----------------
__global__ void build_spt_kernel(const float* __restrict__ sstd, const float* __restrict__ vt,
                                 _Float16* __restrict__ spT) {
    int d = blockIdx.x;      // 0..383
    int c = threadIdx.x;     // 0..383
    spT[d * CCH + c] = (_Float16)(sstd[c] * vt[c * CCH + d]);
}

// ---------------- stage 1 (cast fused): yb[rb][perm(j)] = sum_i noise16[rb][i] * Ht[j][i] ----
// A-tile is built directly from f32 noise: reg-staged load -> cvt f16 -> ds_write_b128,
// with next K-step's loads issued right after the barrier (latency hides under MFMA).
// B-tile stays global_load_lds width=16.
// Epilogue stores yb with a permuted column order (stored col = lm*4+ni within each
// 64-col group) so each lane emits 8B f16x4 stores; oa_kernel inverts the permutation.
__global__ __launch_bounds__(256) void gemm1_kernel(const float* __restrict__ noise,
                                                    const _Float16* __restrict__ Ht,
                                                    _Float16* __restrict__ yb) {
    __shared__ __align__(16) _Float16 As[128 * 32];
    __shared__ __align__(16) _Float16 Bs[128 * 32];
    const int tid  = threadIdx.x;
    const int lane = tid & 63;
    const int w    = tid >> 6;
    const int quad = lane >> 4, lm = lane & 15;
    const int wm   = w >> 1, wn = w & 1;

    // bijective XCD-chunked remap: 4032 blocks, 8 XCDs, 504 logical ids per XCD.
    // Sibling N-blocks (same A-panel) become temporally+spatially adjacent on one XCD.
    const int bid = blockIdx.x + (blockIdx.y << 2);      // hw linear id (x fastest)
    const int lid = (bid & 7) * 504 + (bid >> 3);
    const int n0  = (lid & 3) * 128;
    const int m0  = (lid >> 2) * 128;

    // per-thread A staging coords: rows {arow0, arow0+64}, one 8-wide col segment
    const int colseg = (tid & 3) * 8;                    // 0,8,16,24
    const int arow0  = tid >> 2;                         // 0..63
    const float* asrc0; const float* asrc1;
    int alim0, alim1;
    {
        int m = m0 + arow0;
        int r = m / NB, b = m - r * NB;
        asrc0 = noise + (size_t)r * TPAD + b * HOP;
        alim0 = (b == NB - 1) ? (TPAD - (NB - 1) * HOP) : HOP;   // 192 or 392
        m = m0 + arow0 + 64;
        r = m / NB; b = m - r * NB;
        asrc1 = noise + (size_t)r * TPAD + b * HOP;
        alim1 = (b == NB - 1) ? (TPAD - (NB - 1) * HOP) : HOP;
    }

    f32x4 pv00, pv01, pv10, pv11;
    // segment limits are multiples of 8, i0 is a multiple of 8 -> whole segment valid or zero
#define LOADA(K0) {                                                           \
        int i0 = (K0) + colseg;                                               \
        if (i0 < alim0) { pv00 = *(const f32x4*)(asrc0 + i0);                 \
                          pv01 = *(const f32x4*)(asrc0 + i0 + 4); }           \
        else            { pv00 = (f32x4){}; pv01 = (f32x4){}; }               \
        if (i0 < alim1) { pv10 = *(const f32x4*)(asrc1 + i0);                 \
                          pv11 = *(const f32x4*)(asrc1 + i0 + 4); }           \
        else            { pv10 = (f32x4){}; pv11 = (f32x4){}; }               \
    }

    LOADA(0);

    f32x4 acc[4][4] = {};

    for (int kt = 0; kt < KPAD / 32; ++kt) {
        const int k0 = kt * 32;
        // B: global -> LDS direct (async)
        gload_lds16(Ht + (n0 + arow0) * KPAD + k0 + colseg,
                    Bs + (tid & ~63) * 8);
        gload_lds16(Ht + (n0 + arow0 + 64) * KPAD + k0 + colseg,
                    Bs + (256 + (tid & ~63)) * 8);
        // A: convert prefetched regs, write LDS
        {
            f32x8 v0 = {pv00.x, pv00.y, pv00.z, pv00.w, pv01.x, pv01.y, pv01.z, pv01.w};
            *(f16x8*)(As + arow0 * 32 + colseg) = __builtin_convertvector(v0, f16x8);
            f32x8 v1 = {pv10.x, pv10.y, pv10.z, pv10.w, pv11.x, pv11.y, pv11.z, pv11.w};
            *(f16x8*)(As + (arow0 + 64) * 32 + colseg) = __builtin_convertvector(v1, f16x8);
        }
        __syncthreads();
        if (kt + 1 < KPAD / 32) { LOADA(k0 + 32); }     // prefetch next A under MFMA

        f16x8 a[4], b[4];
#pragma unroll
        for (int mi = 0; mi < 4; ++mi)
            a[mi] = *(const f16x8*)(As + (wm * 64 + mi * 16 + lm) * 32 + quad * 8);
#pragma unroll
        for (int ni = 0; ni < 4; ++ni)
            b[ni] = *(const f16x8*)(Bs + (wn * 64 + ni * 16 + lm) * 32 + quad * 8);
#pragma unroll
        for (int mi = 0; mi < 4; ++mi)
#pragma unroll
            for (int ni = 0; ni < 4; ++ni)
                acc[mi][ni] = __builtin_amdgcn_mfma_f32_16x16x32_f16(a[mi], b[ni], acc[mi][ni], 0, 0, 0);
        __syncthreads();
    }
#undef LOADA

    // epilogue: lane lm holds logical cols {ni*16+lm}; store them contiguously at
    // stored col lm*4+ni -> one 8B f16x4 store per (mi,e); 16 lanes = 128B line.
#pragma unroll
    for (int mi = 0; mi < 4; ++mi)
#pragma unroll
        for (int e = 0; e < 4; ++e) {
            int row = m0 + wm * 64 + mi * 16 + quad * 4 + e;
            f16x4 o = {(_Float16)acc[mi][0][e], (_Float16)acc[mi][1][e],
                       (_Float16)acc[mi][2][e], (_Float16)acc[mi][3][e]};
            *(f16x4*)(yb + (size_t)row * BS + n0 + wn * 64 + lm * 4) = o;
        }
}

// stored col for logical col j (within each 64-col group: lm*4+ni <- ni*16+lm)
__device__ __forceinline__ int permcol(int j) {
    return (j & ~63) | ((j & 15) << 2) | ((j >> 4) & 3);
}

// ---------------- overlap-add + transpose: Yt[n][t][c] ----------------
__global__ __launch_bounds__(256) void oa_kernel(const _Float16* __restrict__ yb,
                                                 _Float16* __restrict__ Yt) {
    __shared__ float Ls[32][33];
    const int tx = threadIdx.x & 31, ty = threadIdx.x >> 5;   // 32 x 8
    const int t0 = blockIdx.x * 32, c0 = blockIdx.y * 32, n = blockIdx.z;
#pragma unroll
    for (int s = 0; s < 4; ++s) {
        int cc = ty + s * 8;
        int r  = n * CCH + c0 + cc;
        int g  = t0 + tx + 120;
        int b  = g / HOP;
        int j  = g - b * HOP;
        size_t base = (size_t)(r * NB + b) * BS;
        float v = (float)yb[base + permcol(j)];
        if (j < 120) v += (float)yb[base - BS + permcol(j + 392)];  // yb[r, b-1, j+392]
        Ls[cc][tx] = v;
    }
    __syncthreads();
#pragma unroll
    for (int s = 0; s < 4; ++s) {
        int tt = ty + s * 8;
        Yt[((size_t)n * TOUT + t0 + tt) * CCH + c0 + tx] = (_Float16)Ls[tx][tt];
    }
}

// ---------------- stage 2: out[(n,t)][d] = sum_c Yt[(n,t)][c] * spT[d][c] ----------------
__global__ __launch_bounds__(256) void gemm2_kernel(const _Float16* __restrict__ Yt,
                                                    const _Float16* __restrict__ spT,
                                                    float* __restrict__ outp) {
    __shared__ __align__(16) _Float16 As[128 * 32];
    __shared__ __align__(16) _Float16 Bs[128 * 32];
    const int tid  = threadIdx.x;
    const int w    = tid >> 6, lane = tid & 63;
    const int quad = lane >> 4, lm = lane & 15;
    const int wm   = w >> 1, wn = w & 1;

    // bijective XCD-chunked remap: 3072 blocks, 384 per XCD
    const int bid = blockIdx.x + blockIdx.y * 3;
    const int lid = (bid & 7) * 384 + (bid >> 3);
    const int n0  = (lid % 3) * 128;
    const int m0  = (lid / 3) * 128;

    f32x4 acc[4][4] = {};

    for (int kt = 0; kt < CCH / 32; ++kt) {
        const int k0 = kt * 32;
#pragma unroll
        for (int ro = 0; ro < 2; ++ro) {
            int gidx = ro * 256 + tid;
            int row  = gidx >> 2;
            int col  = (gidx & 3) * 8;
            gload_lds16(Yt + (size_t)(m0 + row) * CCH + k0 + col,
                        As + (ro * 256 + (tid & ~63)) * 8);
            gload_lds16(spT + (n0 + row) * CCH + k0 + col,
                        Bs + (ro * 256 + (tid & ~63)) * 8);
        }
        __syncthreads();

        f16x8 a[4], b[4];
#pragma unroll
        for (int mi = 0; mi < 4; ++mi)
            a[mi] = *(const f16x8*)(As + (wm * 64 + mi * 16 + lm) * 32 + quad * 8);
#pragma unroll
        for (int ni = 0; ni < 4; ++ni)
            b[ni] = *(const f16x8*)(Bs + (wn * 64 + ni * 16 + lm) * 32 + quad * 8);
#pragma unroll
        for (int mi = 0; mi < 4; ++mi)
#pragma unroll
            for (int ni = 0; ni < 4; ++ni)
                acc[mi][ni] = __builtin_amdgcn_mfma_f32_16x16x32_f16(a[mi], b[ni], acc[mi][ni], 0, 0, 0);
        __syncthreads();
    }

#pragma unroll
    for (int mi = 0; mi < 4; ++mi)
#pragma unroll
        for (int e = 0; e < 4; ++e) {
            int row = m0 + wm * 64 + mi * 16 + quad * 4 + e;
            float* dst = outp + (size_t)row * CCH + n0 + wn * 64 + lm;
#pragma unroll
            for (int ni = 0; ni < 4; ++ni)
                dst[ni * 16] = acc[mi][ni][e];
        }
}

// ---------------- launch ----------------
extern "C" void kernel_launch(void* const* d_in, const int* in_sizes, int n_in,
                              void* d_out, int out_size, void* d_ws, size_t ws_size,
                              hipStream_t stream) {
    const float* noise = (const float*)d_in[0];
    const float* sstd  = (const float*)d_in[1];
    const float* vt    = (const float*)d_in[2];
    const float* kfft  = (const float*)d_in[3];
    float* out = (float*)d_out;

    char* ws = (char*)d_ws;
    // ws layout (16B-aligned):
    float*    h   = (float*)ws;                              // 2048 B
    _Float16* Ht  = (_Float16*)(ws + 2048);                  // 512*416*2  = 425984
    _Float16* spT = (_Float16*)(ws + 428032);                // 384*384*2  = 294912
    _Float16* yb  = (_Float16*)(ws + 722944);                // M1*512*2   = 132120576
    _Float16* Yt  = (_Float16*)(ws + 132843520);             // M2*384*2   = 100663296
    // peak ws usage = 233,506,816 bytes (A16 eliminated)

    build_h_kernel  <<<1, 512, 0, stream>>>(kfft, h);
    build_ht_kernel <<<dim3(512, 2), 256, 0, stream>>>(h, Ht);
    build_spt_kernel<<<CCH, CCH, 0, stream>>>(sstd, vt, spT);

    gemm1_kernel<<<dim3(BS / 128, M1 / 128), 256, 0, stream>>>(noise, Ht, yb);
    oa_kernel   <<<dim3(TOUT / 32, CCH / 32, 2), 256, 0, stream>>>(yb, Yt);
    gemm2_kernel<<<dim3(CCH / 128, M2 / 128), 256, 0, stream>>>(Yt, spT, out);
}